// Round 1
// baseline (535.813 us; speedup 1.0000x reference)
//
#include <hip/hip_runtime.h>
#include <stdint.h>

#define O_DIM 2048
#define I_DIM 4096
#define BS_TOK 8192   // 4*2048 tokens
#define KCB 256
#define PQD 8

typedef __attribute__((ext_vector_type(8))) __bf16 bf16x8;
typedef __attribute__((ext_vector_type(4))) float f32x4;

static __device__ __forceinline__ unsigned short f32_to_bf16(float f) {
    unsigned int u = __float_as_uint(f);
    u += 0x7fffu + ((u >> 16) & 1u);   // round-to-nearest-even
    return (unsigned short)(u >> 16);
}

static __device__ __forceinline__ unsigned int pack2(unsigned short lo, unsigned short hi) {
    return (unsigned int)lo | ((unsigned int)hi << 16);
}

// ---------------- 1. per-row abs-max scale ----------------
__global__ __launch_bounds__(256) void rowscale_kernel(const float* __restrict__ w,
                                                       float* __restrict__ rs) {
    int o = blockIdx.x;
    const float4* row = (const float4*)(w + (size_t)o * I_DIM);
    float m = 0.f;
    for (int i = threadIdx.x; i < I_DIM / 4; i += 256) {
        float4 v = row[i];
        m = fmaxf(m, fmaxf(fmaxf(fabsf(v.x), fabsf(v.y)), fmaxf(fabsf(v.z), fabsf(v.w))));
    }
#pragma unroll
    for (int off = 32; off > 0; off >>= 1)
        m = fmaxf(m, __shfl_down(m, off, 64));
    __shared__ float red[4];
    int wave = threadIdx.x >> 6;
    int lane = threadIdx.x & 63;
    if (lane == 0) red[wave] = m;
    __syncthreads();
    if (threadIdx.x == 0) {
        m = fmaxf(fmaxf(red[0], red[1]), fmaxf(red[2], red[3]));
        rs[o] = fmaxf(m, 1e-6f);
    }
}

// ---------------- 2. fp64 nearest-codeword + dequant to bf16 ----------------
// 2 groups per thread (amortize LDS codebook reads), same weight row per pair.
__global__ __launch_bounds__(256) void assign_kernel(const float* __restrict__ weight,
                                                     const float* __restrict__ codebook,
                                                     const float* __restrict__ rs,
                                                     unsigned short* __restrict__ wq) {
    __shared__ __align__(16) double cb[KCB * PQD];
    __shared__ double cbn[KCB];
    int t = threadIdx.x;
    for (int i = t; i < KCB * PQD; i += 256) cb[i] = (double)codebook[i];
    __syncthreads();
    if (t < KCB) {
        double s = 0.0;
#pragma unroll
        for (int d = 0; d < PQD; ++d) { double v = cb[t * PQD + d]; s += v * v; }
        cbn[t] = s;
    }
    __syncthreads();

    size_t g0 = ((size_t)blockIdx.x * 256 + t) * 2;   // even; pair stays in one row (512 groups/row)
    int o = (int)(g0 >> 9);
    double scale = (double)rs[o];

    const float* wp = weight + g0 * PQD;
    double gv0[PQD], gv1[PQD];
    {
        float4 a = *(const float4*)(wp);
        float4 b = *(const float4*)(wp + 4);
        float4 c = *(const float4*)(wp + 8);
        float4 d = *(const float4*)(wp + 12);
        gv0[0] = (double)a.x / scale; gv0[1] = (double)a.y / scale;
        gv0[2] = (double)a.z / scale; gv0[3] = (double)a.w / scale;
        gv0[4] = (double)b.x / scale; gv0[5] = (double)b.y / scale;
        gv0[6] = (double)b.z / scale; gv0[7] = (double)b.w / scale;
        gv1[0] = (double)c.x / scale; gv1[1] = (double)c.y / scale;
        gv1[2] = (double)c.z / scale; gv1[3] = (double)c.w / scale;
        gv1[4] = (double)d.x / scale; gv1[5] = (double)d.y / scale;
        gv1[6] = (double)d.z / scale; gv1[7] = (double)d.w / scale;
    }

    double best0 = 1e300, best1 = 1e300;
    int bi0 = 0, bi1 = 0;
    for (int c = 0; c < KCB; ++c) {
        double2 p0 = *(const double2*)&cb[c * PQD + 0];
        double2 p1 = *(const double2*)&cb[c * PQD + 2];
        double2 p2 = *(const double2*)&cb[c * PQD + 4];
        double2 p3 = *(const double2*)&cb[c * PQD + 6];
        double dot0 = 0.0, dot1 = 0.0;
        dot0 = fma(p0.x, gv0[0], dot0); dot0 = fma(p0.y, gv0[1], dot0);
        dot0 = fma(p1.x, gv0[2], dot0); dot0 = fma(p1.y, gv0[3], dot0);
        dot0 = fma(p2.x, gv0[4], dot0); dot0 = fma(p2.y, gv0[5], dot0);
        dot0 = fma(p3.x, gv0[6], dot0); dot0 = fma(p3.y, gv0[7], dot0);
        dot1 = fma(p0.x, gv1[0], dot1); dot1 = fma(p0.y, gv1[1], dot1);
        dot1 = fma(p1.x, gv1[2], dot1); dot1 = fma(p1.y, gv1[3], dot1);
        dot1 = fma(p2.x, gv1[4], dot1); dot1 = fma(p2.y, gv1[5], dot1);
        dot1 = fma(p3.x, gv1[6], dot1); dot1 = fma(p3.y, gv1[7], dot1);
        double n = cbn[c];
        double d20 = fma(-2.0, dot0, n);   // == round(-2*dot + n): -2*dot is exact, matches np
        double d21 = fma(-2.0, dot1, n);
        if (d20 < best0) { best0 = d20; bi0 = c; }
        if (d21 < best1) { best1 = d21; bi1 = c; }
    }

    float rsf = (float)scale;
    unsigned short u[16];
#pragma unroll
    for (int d = 0; d < PQD; ++d) u[d] = f32_to_bf16((float)cb[bi0 * PQD + d] * rsf);
#pragma unroll
    for (int d = 0; d < PQD; ++d) u[8 + d] = f32_to_bf16((float)cb[bi1 * PQD + d] * rsf);
    uint4 r0, r1;
    r0.x = pack2(u[0], u[1]);  r0.y = pack2(u[2], u[3]);
    r0.z = pack2(u[4], u[5]);  r0.w = pack2(u[6], u[7]);
    r1.x = pack2(u[8], u[9]);  r1.y = pack2(u[10], u[11]);
    r1.z = pack2(u[12], u[13]); r1.w = pack2(u[14], u[15]);
    *(uint4*)(wq + g0 * PQD) = r0;
    *(uint4*)(wq + g0 * PQD + 8) = r1;
}

// ---------------- 3. x fp32 -> bf16 ----------------
__global__ __launch_bounds__(256) void convert_kernel(const float* __restrict__ x,
                                                      unsigned short* __restrict__ xb) {
    size_t i = ((size_t)blockIdx.x * 256 + threadIdx.x) * 8;
    float4 v0 = *(const float4*)(x + i);
    float4 v1 = *(const float4*)(x + i + 4);
    uint4 r;
    r.x = pack2(f32_to_bf16(v0.x), f32_to_bf16(v0.y));
    r.y = pack2(f32_to_bf16(v0.z), f32_to_bf16(v0.w));
    r.z = pack2(f32_to_bf16(v1.x), f32_to_bf16(v1.y));
    r.w = pack2(f32_to_bf16(v1.z), f32_to_bf16(v1.w));
    *(uint4*)(xb + i) = r;
}

// ---------------- 4. bf16 MFMA GEMM (B^T layout) + bias ----------------
#define TM 128
#define TN 128
#define BK 32

__global__ __launch_bounds__(256) void gemm_bt_bias(const unsigned short* __restrict__ A, // [BS_TOK][I]
                                                    const unsigned short* __restrict__ B, // [O_DIM][I]
                                                    const float* __restrict__ bias,
                                                    float* __restrict__ C) {
    __shared__ __align__(16) unsigned short lds_a[TM * BK]; // 8 KB
    __shared__ __align__(16) unsigned short lds_b[TN * BK]; // 8 KB

    const int t = threadIdx.x;
    const int wave = t >> 6;
    const int lane = t & 63;
    const int quad = lane >> 4;
    const int lr = lane & 15;
    const int bm = blockIdx.y * TM;
    const int bn = blockIdx.x * TN;
    const int wm = (wave >> 1) * 64;
    const int wn = (wave & 1) * 64;
    const int sub_row = lane >> 2;  // 0..15 within a 16-row chunk
    const int seg = lane & 3;       // 16B segment within a 64B row

    f32x4 acc[4][4] = {};

    for (int k0 = 0; k0 < I_DIM; k0 += BK) {
#pragma unroll
        for (int cc = 0; cc < 4; ++cc) {
            int cid = wave + cc * 4;              // 0..15, wave-uniform
            const unsigned short* gsrc;
            unsigned short* ldst;
            if (cid < 8) {
                int row = bm + cid * 16 + sub_row;
                gsrc = A + (size_t)row * I_DIM + k0 + seg * 8;
                ldst = lds_a + cid * 512;
            } else {
                int row = bn + (cid - 8) * 16 + sub_row;
                gsrc = B + (size_t)row * I_DIM + k0 + seg * 8;
                ldst = lds_b + (cid - 8) * 512;
            }
            __builtin_amdgcn_global_load_lds((const __attribute__((address_space(1))) void*)gsrc,
                                             (__attribute__((address_space(3))) void*)ldst,
                                             16, 0, 0);
        }
        __syncthreads();

        bf16x8 af[4], bfr[4];
#pragma unroll
        for (int i = 0; i < 4; ++i)
            af[i] = *(const bf16x8*)&lds_a[(wm + i * 16 + lr) * BK + quad * 8];
#pragma unroll
        for (int j = 0; j < 4; ++j)
            bfr[j] = *(const bf16x8*)&lds_b[(wn + j * 16 + lr) * BK + quad * 8];
#pragma unroll
        for (int i = 0; i < 4; ++i)
#pragma unroll
            for (int j = 0; j < 4; ++j)
                acc[i][j] = __builtin_amdgcn_mfma_f32_16x16x32_bf16(af[i], bfr[j], acc[i][j], 0, 0, 0);
        __syncthreads();
    }

#pragma unroll
    for (int i = 0; i < 4; ++i) {
        int mrow_base = bm + wm + i * 16 + quad * 4;
#pragma unroll
        for (int j = 0; j < 4; ++j) {
            int n = bn + wn + j * 16 + lr;
            float bv = bias[n];
#pragma unroll
            for (int r = 0; r < 4; ++r) {
                int m = mrow_base + r;
                C[(size_t)m * O_DIM + n] = acc[i][j][r] + bv;
            }
        }
    }
}

extern "C" void kernel_launch(void* const* d_in, const int* in_sizes, int n_in,
                              void* d_out, int out_size, void* d_ws, size_t ws_size,
                              hipStream_t stream) {
    const float* x        = (const float*)d_in[0];
    const float* weight   = (const float*)d_in[1];
    const float* codebook = (const float*)d_in[2];
    const float* bias     = (const float*)d_in[3];
    float* out = (float*)d_out;

    char* ws = (char*)d_ws;
    float* rs = (float*)ws;                                            // 8 KB
    unsigned short* wq = (unsigned short*)(ws + 8192);                 // 16 MB
    unsigned short* xb = (unsigned short*)(ws + 8192 + (size_t)O_DIM * I_DIM * 2); // 64 MB

    rowscale_kernel<<<O_DIM, 256, 0, stream>>>(weight, rs);
    assign_kernel<<<(O_DIM * (I_DIM / PQD)) / (256 * 2), 256, 0, stream>>>(weight, codebook, rs, wq);
    convert_kernel<<<((size_t)BS_TOK * I_DIM / 8) / 256, 256, 0, stream>>>(x, xb);
    gemm_bt_bias<<<dim3(O_DIM / TN, BS_TOK / TM), 256, 0, stream>>>(xb, wq, bias, out);
}